// Round 1
// baseline (1208.982 us; speedup 1.0000x reference)
//
#include <hip/hip_runtime.h>
#include <hip/hip_bf16.h>

// Problem constants (from reference)
#define E_   8
#define D_   1024
#define H_   4096
#define T_   8192      // B*S tokens
#define TM   128       // GEMM M/N tile
#define BK   64        // GEMM K chunk (bf16)
#define CAP  17408     // 136*128 >= 16384 + 8*127 padded capacity
#define NBY  136       // CAP/TM

typedef __attribute__((ext_vector_type(8))) short short8;   // 8 bf16 = 4 VGPRs (MFMA A/B frag)
typedef __attribute__((ext_vector_type(4))) float floatx4;  // MFMA C/D frag

__device__ __forceinline__ unsigned short f2bf(float f) {
    unsigned u = __float_as_uint(f);
    u += 0x7fffu + ((u >> 16) & 1u);   // RNE truncate to bf16
    return (unsigned short)(u >> 16);
}

// direct global->LDS async copy, 16B/lane; lds base must be wave-uniform
#define GLP16(g, l)                                                             \
    __builtin_amdgcn_global_load_lds((const __attribute__((address_space(1))) void*)(g), \
                                     (__attribute__((address_space(3))) void*)(l), 16, 0, 0)

// ---------------- Router: 1 wave per token ----------------
__global__ __launch_bounds__(64) void router_kernel(
    const float* __restrict__ x, const float* __restrict__ Wr,
    int* __restrict__ cnt, int* __restrict__ tok_list, float* __restrict__ w_list)
{
    int t = blockIdx.x;
    int lane = threadIdx.x;
    const float* xr = x + (size_t)t * D_;
    float acc[E_];
#pragma unroll
    for (int e = 0; e < E_; ++e) acc[e] = 0.f;
    for (int it = 0; it < D_ / 64; ++it) {
        float xv = xr[lane + it * 64];
#pragma unroll
        for (int e = 0; e < E_; ++e) acc[e] += xv * Wr[e * D_ + lane + it * 64];
    }
#pragma unroll
    for (int e = 0; e < E_; ++e) {
#pragma unroll
        for (int off = 32; off; off >>= 1) acc[e] += __shfl_xor(acc[e], off);
    }
    if (lane == 0) {
        float m = acc[0];
#pragma unroll
        for (int e = 1; e < E_; ++e) m = fmaxf(m, acc[e]);
        float p[E_]; float s = 0.f;
#pragma unroll
        for (int e = 0; e < E_; ++e) { p[e] = expf(acc[e] - m); s += p[e]; }
        float inv = 1.f / s;
        int i1 = 0; float v1 = p[0];
#pragma unroll
        for (int e = 1; e < E_; ++e) if (p[e] > v1) { v1 = p[e]; i1 = e; }
        int i2 = -1; float v2 = -1.f;
#pragma unroll
        for (int e = 0; e < E_; ++e) { if (e == i1) continue; if (p[e] > v2) { v2 = p[e]; i2 = e; } }
        v1 *= inv; v2 *= inv;
        int pos1 = atomicAdd(&cnt[i1], 1);
        tok_list[i1 * T_ + pos1] = t; w_list[i1 * T_ + pos1] = v1;
        int pos2 = atomicAdd(&cnt[i2], 1);
        tok_list[i2 * T_ + pos2] = t; w_list[i2 * T_ + pos2] = v2;
    }
}

// ---------------- Prefix: 128-aligned expert regions ----------------
__global__ void offsets_kernel(const int* __restrict__ cnt, int* __restrict__ start)
{
    if (threadIdx.x == 0) {
        int s = 0;
        for (int e = 0; e < E_; ++e) {
            start[e] = s;
            s += (cnt[e] + TM - 1) / TM * TM;
        }
        start[E_] = s;
    }
}

// ---------------- Gather x rows -> bf16, record token/weight ----------------
__global__ __launch_bounds__(256) void gather_kernel(
    const float* __restrict__ x, const int* __restrict__ cnt, const int* __restrict__ start,
    const int* __restrict__ tok_list, const float* __restrict__ w_list,
    unsigned short* __restrict__ xg, int* __restrict__ tok, float* __restrict__ wgt)
{
    int row = blockIdx.x;
    int tid = threadIdx.x;
    int tot = start[E_];
    if (row >= tot) {
        if (tid == 0) { tok[row] = -1; wgt[row] = 0.f; }
        return;
    }
    int e = 0;
    while (e < E_ - 1 && row >= start[e + 1]) ++e;
    int idx = row - start[e];
    unsigned short* dst = xg + (size_t)row * D_;
    if (idx < cnt[e]) {
        int t = tok_list[e * T_ + idx];
        if (tid == 0) { tok[row] = t; wgt[row] = w_list[e * T_ + idx]; }
        const float4* src = (const float4*)(x + (size_t)t * D_);
        float4 v = src[tid];
        ushort4 o; o.x = f2bf(v.x); o.y = f2bf(v.y); o.z = f2bf(v.z); o.w = f2bf(v.w);
        ((ushort4*)dst)[tid] = o;
    } else {
        if (tid == 0) { tok[row] = -1; wgt[row] = 0.f; }
        ((ushort4*)dst)[tid] = make_ushort4(0, 0, 0, 0);  // zero pad rows
    }
}

// ---------------- Transpose + fp32->bf16: in[E][R][C] -> out[E][C][R] ----------------
__global__ __launch_bounds__(256) void transpose_cvt(
    const float* __restrict__ in, unsigned short* __restrict__ out, int R, int C)
{
    __shared__ float tile[32][33];
    int e = blockIdx.z;
    int c0 = blockIdx.x * 32, r0 = blockIdx.y * 32;
    const float* src = in + (size_t)e * R * C;
    unsigned short* dst = out + (size_t)e * R * C;
    int tx = threadIdx.x & 31, ty = threadIdx.x >> 5;
#pragma unroll
    for (int i = 0; i < 32; i += 8)
        tile[ty + i][tx] = src[(size_t)(r0 + ty + i) * C + c0 + tx];
    __syncthreads();
#pragma unroll
    for (int i = 0; i < 32; i += 8)
        dst[(size_t)(c0 + ty + i) * R + r0 + tx] = f2bf(tile[tx][ty + i]);
}

// ---------------- fc1: h = gelu(Xg @ W1 + b1), bf16 out ----------------
// Xg: [CAP][D_] bf16 row-major. W1t: [E][H_][D_] bf16 (B^T). h: [CAP][H_] bf16.
__global__ __launch_bounds__(256) void fc1_kernel(
    const unsigned short* __restrict__ xg, const unsigned short* __restrict__ w1t,
    const float* __restrict__ b1, const int* __restrict__ start, unsigned short* __restrict__ h)
{
    __shared__ __align__(16) unsigned short Asm[TM * BK];
    __shared__ __align__(16) unsigned short Bsm[TM * BK];

    int row0 = blockIdx.y * TM;
    int tot = start[E_];
    if (row0 >= tot) return;
    int e = 0;
    while (e < E_ - 1 && row0 >= start[e + 1]) ++e;

    int n0 = blockIdx.x * TM;
    const unsigned short* Ag = xg + (size_t)row0 * D_;
    const unsigned short* Bg = w1t + (size_t)e * H_ * D_ + (size_t)n0 * D_;

    int tid = threadIdx.x;
    int wid = tid >> 6, lane = tid & 63;
    int wm = wid >> 1, wn = wid & 1;
    int quad = lane >> 4, r16 = lane & 15;
    int srow = (lane >> 3);          // 0..7 within 8-row slab
    int scol = (lane & 7) * 8;       // bf16 offset, 16B per lane

    floatx4 acc[4][4];
#pragma unroll
    for (int i = 0; i < 4; ++i)
#pragma unroll
        for (int j = 0; j < 4; ++j) acc[i][j] = (floatx4){0.f, 0.f, 0.f, 0.f};

    for (int kc = 0; kc < D_ / BK; ++kc) {
        int k0 = kc * BK;
#pragma unroll
        for (int q = 0; q < 4; ++q) {
            int rb = wid * 32 + q * 8;
            GLP16(Ag + (size_t)(rb + srow) * D_ + k0 + scol, Asm + rb * BK);
            GLP16(Bg + (size_t)(rb + srow) * D_ + k0 + scol, Bsm + rb * BK);
        }
        __syncthreads();
#pragma unroll
        for (int ks = 0; ks < 2; ++ks) {
            short8 af[4], bfr[4];
#pragma unroll
            for (int i = 0; i < 4; ++i)
                af[i] = *(const short8*)(Asm + (wm * 64 + i * 16 + r16) * BK + ks * 32 + quad * 8);
#pragma unroll
            for (int j = 0; j < 4; ++j)
                bfr[j] = *(const short8*)(Bsm + (wn * 64 + j * 16 + r16) * BK + ks * 32 + quad * 8);
#pragma unroll
            for (int i = 0; i < 4; ++i)
#pragma unroll
                for (int j = 0; j < 4; ++j)
                    acc[i][j] = __builtin_amdgcn_mfma_f32_16x16x32_bf16(af[i], bfr[j], acc[i][j], 0, 0, 0);
        }
        __syncthreads();
    }

    const float* b1e = b1 + (size_t)e * H_;
    float bj[4];
#pragma unroll
    for (int j = 0; j < 4; ++j) bj[j] = b1e[n0 + wn * 64 + j * 16 + r16];
#pragma unroll
    for (int i = 0; i < 4; ++i) {
#pragma unroll
        for (int r = 0; r < 4; ++r) {
            size_t rowg = (size_t)row0 + wm * 64 + i * 16 + quad * 4 + r;
            unsigned short* hp = h + rowg * H_ + n0 + wn * 64 + r16;
#pragma unroll
            for (int j = 0; j < 4; ++j) {
                float v = acc[i][j][r] + bj[j];
                v = 0.5f * v * (1.0f + erff(v * 0.70710678118654752f));  // exact gelu
                hp[j * 16] = f2bf(v);
            }
        }
    }
}

// ---------------- fc2: out[tok] += w * (h @ W2 + b2) ----------------
// h: [CAP][H_] bf16. W2t: [E][D_][H_] bf16 (B^T). out: [T_][D_] fp32 (pre-zeroed).
__global__ __launch_bounds__(256) void fc2_kernel(
    const unsigned short* __restrict__ h, const unsigned short* __restrict__ w2t,
    const float* __restrict__ b2, const int* __restrict__ start,
    const int* __restrict__ tok, const float* __restrict__ wgt, float* __restrict__ out)
{
    __shared__ __align__(16) unsigned short Asm[TM * BK];
    __shared__ __align__(16) unsigned short Bsm[TM * BK];

    int row0 = blockIdx.y * TM;
    int tot = start[E_];
    if (row0 >= tot) return;
    int e = 0;
    while (e < E_ - 1 && row0 >= start[e + 1]) ++e;

    int n0 = blockIdx.x * TM;
    const unsigned short* Ag = h + (size_t)row0 * H_;
    const unsigned short* Bg = w2t + (size_t)e * D_ * H_ + (size_t)n0 * H_;

    int tid = threadIdx.x;
    int wid = tid >> 6, lane = tid & 63;
    int wm = wid >> 1, wn = wid & 1;
    int quad = lane >> 4, r16 = lane & 15;
    int srow = (lane >> 3);
    int scol = (lane & 7) * 8;

    floatx4 acc[4][4];
#pragma unroll
    for (int i = 0; i < 4; ++i)
#pragma unroll
        for (int j = 0; j < 4; ++j) acc[i][j] = (floatx4){0.f, 0.f, 0.f, 0.f};

    for (int kc = 0; kc < H_ / BK; ++kc) {
        int k0 = kc * BK;
#pragma unroll
        for (int q = 0; q < 4; ++q) {
            int rb = wid * 32 + q * 8;
            GLP16(Ag + (size_t)(rb + srow) * H_ + k0 + scol, Asm + rb * BK);
            GLP16(Bg + (size_t)(rb + srow) * H_ + k0 + scol, Bsm + rb * BK);
        }
        __syncthreads();
#pragma unroll
        for (int ks = 0; ks < 2; ++ks) {
            short8 af[4], bfr[4];
#pragma unroll
            for (int i = 0; i < 4; ++i)
                af[i] = *(const short8*)(Asm + (wm * 64 + i * 16 + r16) * BK + ks * 32 + quad * 8);
#pragma unroll
            for (int j = 0; j < 4; ++j)
                bfr[j] = *(const short8*)(Bsm + (wn * 64 + j * 16 + r16) * BK + ks * 32 + quad * 8);
#pragma unroll
            for (int i = 0; i < 4; ++i)
#pragma unroll
                for (int j = 0; j < 4; ++j)
                    acc[i][j] = __builtin_amdgcn_mfma_f32_16x16x32_bf16(af[i], bfr[j], acc[i][j], 0, 0, 0);
        }
        __syncthreads();
    }

    const float* b2e = b2 + (size_t)e * D_;
    float bj[4];
#pragma unroll
    for (int j = 0; j < 4; ++j) bj[j] = b2e[n0 + wn * 64 + j * 16 + r16];
#pragma unroll
    for (int i = 0; i < 4; ++i) {
#pragma unroll
        for (int r = 0; r < 4; ++r) {
            int row = row0 + wm * 64 + i * 16 + quad * 4 + r;
            int t = tok[row];
            if (t < 0) continue;
            float w = wgt[row];
            float* op = out + (size_t)t * D_ + n0 + wn * 64 + r16;
#pragma unroll
            for (int j = 0; j < 4; ++j)
                atomicAdd(&op[j * 16], w * (acc[i][j][r] + bj[j]));
        }
    }
}

// ---------------- Launch ----------------
extern "C" void kernel_launch(void* const* d_in, const int* in_sizes, int n_in,
                              void* d_out, int out_size, void* d_ws, size_t ws_size,
                              hipStream_t stream)
{
    const float* x  = (const float*)d_in[0];
    const float* Wr = (const float*)d_in[1];
    const float* W1 = (const float*)d_in[2];
    const float* b1 = (const float*)d_in[3];
    const float* W2 = (const float*)d_in[4];
    const float* b2 = (const float*)d_in[5];
    float* out = (float*)d_out;

    // ws layout (needs ~300 MB)
    char* ws = (char*)d_ws;
    int*   cnt      = (int*)ws;                       // 8 ints
    int*   start    = (int*)(ws + 64);                // 9 ints
    int*   tok_list = (int*)(ws + 256);               // 8*8192 = 256 KiB
    float* w_list   = (float*)(ws + 256 + 262144);    // 256 KiB
    int*   tok      = (int*)(ws + 256 + 2 * 262144);  // CAP ints
    float* wgt      = (float*)(ws + 256 + 2 * 262144 + 69632);
    char* p = ws + (1u << 20);
    unsigned short* xg  = (unsigned short*)p; p += (size_t)CAP * D_ * 2;      // 35.7 MB
    unsigned short* h   = (unsigned short*)p; p += (size_t)CAP * H_ * 2;      // 142.6 MB
    unsigned short* w1t = (unsigned short*)p; p += (size_t)E_ * D_ * H_ * 2;  // 67 MB
    unsigned short* w2t = (unsigned short*)p;                                 // 67 MB
    (void)ws_size; (void)in_sizes; (void)n_in; (void)out_size;

    hipMemsetAsync(ws, 0, 256, stream);                                // zero cnt/start
    hipMemsetAsync(out, 0, (size_t)T_ * D_ * sizeof(float), stream);   // out accumulates via atomics

    transpose_cvt<<<dim3(H_ / 32, D_ / 32, E_), 256, 0, stream>>>(W1, w1t, D_, H_);
    transpose_cvt<<<dim3(D_ / 32, H_ / 32, E_), 256, 0, stream>>>(W2, w2t, H_, D_);
    router_kernel<<<T_, 64, 0, stream>>>(x, Wr, cnt, tok_list, w_list);
    offsets_kernel<<<1, 64, 0, stream>>>(cnt, start);
    gather_kernel<<<CAP, 256, 0, stream>>>(x, cnt, start, tok_list, w_list, xg, tok, wgt);
    fc1_kernel<<<dim3(H_ / TM, NBY), 256, 0, stream>>>(xg, w1t, b1, start, h);
    fc2_kernel<<<dim3(D_ / TM, NBY), 256, 0, stream>>>(h, w2t, b2, start, tok, wgt, out);
}